// Round 6
// baseline (274.799 us; speedup 1.0000x reference)
//
#include <hip/hip_runtime.h>
#include <hip/hip_bf16.h>

#define T_TOK 2048
#define DDIM  1024
#define HDIM  2048
#define NEXP  8
#define NSEG  9   // 8 routed + 1 shared

typedef unsigned short u16;
typedef __attribute__((ext_vector_type(4))) float f32x4;
typedef __attribute__((ext_vector_type(8))) short bf16x8;
typedef __attribute__((ext_vector_type(4))) unsigned short u16x4;

__device__ __forceinline__ u16 f2bf(float x) {
  union { float f; unsigned int u; } v; v.f = x;
  unsigned int r = v.u + 0x7fffu + ((v.u >> 16) & 1u);
  return (u16)(r >> 16);
}
__device__ __forceinline__ float gelu_exact(float x) {
  return 0.5f * x * (1.0f + erff(x * 0.70710678118654752f));
}
// chunk swizzle for 64B rows (4 x 16B chunks)
__device__ __forceinline__ int swz4(int row) {
  return (row & 3) ^ ((row >> 2) & 3);
}

__device__ __forceinline__ void gload16(const void* g, void* l) {
  __builtin_amdgcn_global_load_lds(
      (const __attribute__((address_space(1))) unsigned int*)g,
      (__attribute__((address_space(3))) unsigned int*)l, 16, 0, 0);
}

// ---------------- router: logits, softmax, top-2, lists, bf16 X ----------------
__global__ __launch_bounds__(256) void router_kernel(
    const float* __restrict__ x, const float* __restrict__ rw,
    const float* __restrict__ rb, u16* __restrict__ xb,
    float* __restrict__ weights, int* __restrict__ counts,
    int* __restrict__ lists)
{
  int wv = threadIdx.x >> 6, lane = threadIdx.x & 63;
  int t = blockIdx.x * 4 + wv;            // one wave per token
  const float* xrow = x + (size_t)t * DDIM;
  float acc[NEXP];
#pragma unroll
  for (int e = 0; e < NEXP; e++) acc[e] = 0.f;
#pragma unroll
  for (int i = 0; i < 4; i++) {
    int d0 = i * 256 + lane * 4;
    f32x4 xv = *(const f32x4*)(xrow + d0);
    u16x4 pk;
#pragma unroll
    for (int j = 0; j < 4; j++) {
      float xs = xv[j];
      pk[j] = f2bf(xs);
      const float* wr = rw + (size_t)(d0 + j) * NEXP;
#pragma unroll
      for (int e = 0; e < NEXP; e++) acc[e] = fmaf(xs, wr[e], acc[e]);
    }
    *(u16x4*)(xb + (size_t)t * DDIM + d0) = pk;
  }
#pragma unroll
  for (int off = 32; off >= 1; off >>= 1)
#pragma unroll
    for (int e = 0; e < NEXP; e++) acc[e] += __shfl_xor(acc[e], off);

  if (lane == 0) {
    float lg[NEXP], mx = -1e30f;
#pragma unroll
    for (int e = 0; e < NEXP; e++) { lg[e] = acc[e] + rb[e]; mx = fmaxf(mx, lg[e]); }
    float p[NEXP], s = 0.f;
#pragma unroll
    for (int e = 0; e < NEXP; e++) { p[e] = expf(lg[e] - mx); s += p[e]; }
    float inv = 1.0f / s;
#pragma unroll
    for (int e = 0; e < NEXP; e++) p[e] *= inv;
    int i1 = 0;
#pragma unroll
    for (int e = 1; e < NEXP; e++) if (p[e] > p[i1]) i1 = e;
    int i2 = (i1 == 0) ? 1 : 0;
#pragma unroll
    for (int e = 0; e < NEXP; e++) if (e != i1 && p[e] > p[i2]) i2 = e;
#pragma unroll
    for (int e = 0; e < NEXP; e++)
      weights[(size_t)t * NEXP + e] = (e == i1) ? p[i1] : (e == i2) ? p[i2] : 0.f;
    int p1 = atomicAdd(counts + i1, 1); lists[i1 * T_TOK + p1] = t;
    int p2 = atomicAdd(counts + i2, 1); lists[i2 * T_TOK + p2] = t;
    lists[NEXP * T_TOK + t] = t;        // shared segment: identity
  }
}

// seg offsets + compact y-tile table (e*256+my for non-empty 128-row tiles)
__global__ void seg_kernel(int* counts, int* segoff, int* ytab, int* nyt) {
  counts[NEXP] = T_TOK;
  int off = 0, n = 0;
  for (int e = 0; e < NSEG; e++) {
    segoff[e] = off;
    int c = counts[e];
    for (int my = 0; my * 128 < c; my++) ytab[n++] = e * 256 + my;
    off += c;
  }
  *nyt = n;
}

// ------------- transpose + fp32->bf16 cast: [z][R][C] -> [z][C][R] -------------
__global__ __launch_bounds__(256) void transpose_bf16_kernel(
    const float* __restrict__ rin, const float* __restrict__ sin_,
    u16* __restrict__ rout, u16* __restrict__ sout, int R, int C)
{
  __shared__ float tile[32][33];
  int b = blockIdx.z;
  const float* inb = (b < NEXP) ? rin + (size_t)b * R * C : sin_;
  u16* outb = (b < NEXP) ? rout + (size_t)b * R * C : sout;
  int r0 = blockIdx.y * 32, c0 = blockIdx.x * 32;
  int tx = threadIdx.x & 31, ty = threadIdx.x >> 5;
#pragma unroll
  for (int j = 0; j < 4; j++) {
    int r = ty + j * 8;
    tile[r][tx] = inb[(size_t)(r0 + r) * C + c0 + tx];
  }
  __syncthreads();
#pragma unroll
  for (int j = 0; j < 4; j++) {
    int rr = ty + j * 8;
    outb[(size_t)(c0 + rr) * R + r0 + tx] = f2bf(tile[tx][rr]);
  }
}

// =====================================================================
// GEMM core: 128x128 tile, BK=32, 4 waves, TRIPLE-buffered LDS (48 KB),
// ONE raw barrier per K-step, counted vmcnt (never 0 in steady state):
//   iter s: issue stage(s+1 -> buf[(s+1)%3]); vmcnt(4); s_barrier;
//           sched_barrier; ds_read+MFMA on buf[s%3]
// Race-freedom: buf[s%3] is next overwritten by stage(s+3), which is
// issued only after barrier #s+1 -- and no wave passes barrier #s+1
// until every wave finished compute(s). vmcnt(4) with stage(s+1)'s 4
// loads newer ensures stage(s) landed regardless of extra VM ops.
// =====================================================================

// ---------------- GEMM1: H1 = gelu(gather(X) @ W1 + b1), bf16 out ----------------
__global__ __launch_bounds__(256) void gemm1_kernel(
    const u16* __restrict__ Xb, const u16* __restrict__ rw1t,
    const u16* __restrict__ sw1t, const float* __restrict__ rb1,
    const float* __restrict__ sb1, const int* __restrict__ counts,
    const int* __restrict__ segoff, const int* __restrict__ lists,
    const int* __restrict__ ytab, const int* __restrict__ nyt,
    u16* __restrict__ H1)
{
  __shared__ u16 Alds[3][128 * 32];   // 8 KB x3
  __shared__ u16 Blds[3][128 * 32];   // 8 KB x3

  int tid = threadIdx.x, lane = tid & 63;
  int wv = tid >> 6, wm = wv >> 1, wn = wv & 1;
  int kc = lane >> 4, lr = lane & 15;

  // staging: chunk i = r*256+tid; row=i>>2, dest chunk=i&3 (linear dest);
  // global source chunk = (i&3) ^ swz4(row)
  int srow[2], soff[2];
#pragma unroll
  for (int r = 0; r < 2; r++) {
    int i = r * 256 + tid;
    srow[r] = i >> 2;
    soff[r] = (((i & 3) ^ swz4(i >> 2)) * 8);
  }
  // fragment read offsets (elems): row ra, chunk kc ^ swz4(ra)
  int aoff[4], boff[4];
#pragma unroll
  for (int f = 0; f < 4; f++) {
    int ra = wm * 64 + f * 16 + lr;
    int rb_ = wn * 64 + f * 16 + lr;
    aoff[f] = ra * 32 + ((kc ^ swz4(ra)) * 8);
    boff[f] = rb_ * 32 + ((kc ^ swz4(rb_)) * 8);
  }

  int ntile = nyt[0] * (HDIM / 128);
  for (int t = blockIdx.x; t < ntile; t += gridDim.x) {
    int yt = t >> 4, nx = t & 15;
    int em = ytab[yt];
    int e = em >> 8, m0 = (em & 255) * 128, n0 = nx * 128;
    int cnt = counts[e];
    const u16* Bt = (e < NEXP) ? (rw1t + (size_t)e * HDIM * DDIM) : sw1t;
    const float* bias = (e < NEXP) ? (rb1 + (size_t)e * HDIM) : sb1;
    const int* list = lists + e * T_TOK;
    int seg = segoff[e];

    size_t abase[2], bbase[2];
#pragma unroll
    for (int r = 0; r < 2; r++) {
      int tok = list[min(m0 + srow[r], cnt - 1)];
      abase[r] = (size_t)tok * DDIM + soff[r];
      bbase[r] = (size_t)(n0 + srow[r]) * DDIM + soff[r];
    }

    f32x4 acc[4][4];
#pragma unroll
    for (int i = 0; i < 4; i++)
#pragma unroll
      for (int j = 0; j < 4; j++) acc[i][j] = (f32x4){0.f, 0.f, 0.f, 0.f};

    // prologue: stage step 0 into buf 0 (4 loads in flight)
#pragma unroll
    for (int r = 0; r < 2; r++) {
      int i = r * 256 + tid;
      gload16(Xb + abase[r], &Alds[0][i * 8]);
      gload16(Bt + bbase[r], &Blds[0][i * 8]);
    }

    const int NS = DDIM / 32;   // 32 steps
    int cur = 0;
    for (int s = 0; s < NS; s++) {
      int nxt = cur + 1; if (nxt == 3) nxt = 0;
      if (s + 1 < NS) {
        int kk = (s + 1) * 32;
        u16* Ad = &Alds[nxt][0];
        u16* Bd = &Blds[nxt][0];
#pragma unroll
        for (int r = 0; r < 2; r++) {
          int i = r * 256 + tid;
          gload16(Xb + abase[r] + kk, Ad + i * 8);
          gload16(Bt + bbase[r] + kk, Bd + i * 8);
        }
        asm volatile("s_waitcnt vmcnt(4)" ::: "memory");
      } else {
        asm volatile("s_waitcnt vmcnt(0)" ::: "memory");
      }
      __builtin_amdgcn_s_barrier();
      __builtin_amdgcn_sched_barrier(0);

      const u16* Ac = &Alds[cur][0];
      const u16* Bc = &Blds[cur][0];
      bf16x8 af[4], bfr[4];
#pragma unroll
      for (int f = 0; f < 4; f++) {
        af[f]  = *(const bf16x8*)(Ac + aoff[f]);
        bfr[f] = *(const bf16x8*)(Bc + boff[f]);
      }
#pragma unroll
      for (int mf = 0; mf < 4; mf++)
#pragma unroll
        for (int nf = 0; nf < 4; nf++)
          acc[mf][nf] = __builtin_amdgcn_mfma_f32_16x16x32_bf16(af[mf], bfr[nf], acc[mf][nf], 0, 0, 0);
      cur = nxt;
    }

#pragma unroll
    for (int nf = 0; nf < 4; nf++) {
      int col = n0 + wn * 64 + nf * 16 + lr;
      float b = bias[col];
#pragma unroll
      for (int mf = 0; mf < 4; mf++) {
#pragma unroll
        for (int rg = 0; rg < 4; rg++) {
          int mt = wm * 64 + mf * 16 + kc * 4 + rg;
          if (m0 + mt < cnt) {
            float v = acc[mf][nf][rg] + b;
            H1[(size_t)(seg + m0 + mt) * HDIM + col] = f2bf(gelu_exact(v));
          }
        }
      }
    }
    // all waves must finish compute(NS-1)/epilogue before next tile's
    // prologue overwrites buf0/buf1 (uniform per-block trip count).
    __builtin_amdgcn_s_barrier();
    __builtin_amdgcn_sched_barrier(0);
  }
}

// ------------- GEMM2: out[tok] += w * (H1seg @ W2 + b2), fp32 atomics -------------
// K split in 2 halves of 1024 (bias added by half 0 only).
__global__ __launch_bounds__(256) void gemm2_kernel(
    const u16* __restrict__ H1, const u16* __restrict__ rw2t,
    const u16* __restrict__ sw2t, const float* __restrict__ rb2,
    const float* __restrict__ sb2, const float* __restrict__ weights,
    const int* __restrict__ counts, const int* __restrict__ segoff,
    const int* __restrict__ lists, const int* __restrict__ ytab,
    const int* __restrict__ nyt, float* __restrict__ out)
{
  __shared__ u16 Alds[3][128 * 32];
  __shared__ u16 Blds[3][128 * 32];

  int tid = threadIdx.x, lane = tid & 63;
  int wv = tid >> 6, wm = wv >> 1, wn = wv & 1;
  int kc = lane >> 4, lr = lane & 15;

  int srow[2], soff[2];
#pragma unroll
  for (int r = 0; r < 2; r++) {
    int i = r * 256 + tid;
    srow[r] = i >> 2;
    soff[r] = (((i & 3) ^ swz4(i >> 2)) * 8);
  }
  int aoff[4], boff[4];
#pragma unroll
  for (int f = 0; f < 4; f++) {
    int ra = wm * 64 + f * 16 + lr;
    int rb_ = wn * 64 + f * 16 + lr;
    aoff[f] = ra * 32 + ((kc ^ swz4(ra)) * 8);
    boff[f] = rb_ * 32 + ((kc ^ swz4(rb_)) * 8);
  }

  int ntile = nyt[0] * (DDIM / 128) * 2;
  for (int t = blockIdx.x; t < ntile; t += gridDim.x) {
    int kh = t & 1, nx = (t >> 1) & 7, yt = t >> 4;
    int em = ytab[yt];
    int e = em >> 8, m0 = (em & 255) * 128, n0 = nx * 128;
    int cnt = counts[e];
    const u16* Bt = (e < NEXP) ? (rw2t + (size_t)e * DDIM * HDIM) : sw2t;
    const float* bias = (e < NEXP) ? (rb2 + (size_t)e * DDIM) : sb2;
    const int* list = lists + e * T_TOK;
    int seg = segoff[e];
    int k0 = kh * 1024;

    size_t abase[2], bbase[2];
#pragma unroll
    for (int r = 0; r < 2; r++) {
      abase[r] = (size_t)(seg + min(m0 + srow[r], cnt - 1)) * HDIM + k0 + soff[r];
      bbase[r] = (size_t)(n0 + srow[r]) * HDIM + k0 + soff[r];
    }

    f32x4 acc[4][4];
#pragma unroll
    for (int i = 0; i < 4; i++)
#pragma unroll
      for (int j = 0; j < 4; j++) acc[i][j] = (f32x4){0.f, 0.f, 0.f, 0.f};

#pragma unroll
    for (int r = 0; r < 2; r++) {
      int i = r * 256 + tid;
      gload16(H1 + abase[r], &Alds[0][i * 8]);
      gload16(Bt + bbase[r], &Blds[0][i * 8]);
    }

    const int NS = 1024 / 32;   // 32 steps
    int cur = 0;
    for (int s = 0; s < NS; s++) {
      int nxt = cur + 1; if (nxt == 3) nxt = 0;
      if (s + 1 < NS) {
        int kk = (s + 1) * 32;
        u16* Ad = &Alds[nxt][0];
        u16* Bd = &Blds[nxt][0];
#pragma unroll
        for (int r = 0; r < 2; r++) {
          int i = r * 256 + tid;
          gload16(H1 + abase[r] + kk, Ad + i * 8);
          gload16(Bt + bbase[r] + kk, Bd + i * 8);
        }
        asm volatile("s_waitcnt vmcnt(4)" ::: "memory");
      } else {
        asm volatile("s_waitcnt vmcnt(0)" ::: "memory");
      }
      __builtin_amdgcn_s_barrier();
      __builtin_amdgcn_sched_barrier(0);

      const u16* Ac = &Alds[cur][0];
      const u16* Bc = &Blds[cur][0];
      bf16x8 af[4], bfr[4];
#pragma unroll
      for (int f = 0; f < 4; f++) {
        af[f]  = *(const bf16x8*)(Ac + aoff[f]);
        bfr[f] = *(const bf16x8*)(Bc + boff[f]);
      }
#pragma unroll
      for (int mf = 0; mf < 4; mf++)
#pragma unroll
        for (int nf = 0; nf < 4; nf++)
          acc[mf][nf] = __builtin_amdgcn_mfma_f32_16x16x32_bf16(af[mf], bfr[nf], acc[mf][nf], 0, 0, 0);
      cur = nxt;
    }

    float biasv[4];
#pragma unroll
    for (int nf = 0; nf < 4; nf++)
      biasv[nf] = (kh == 0) ? bias[n0 + wn * 64 + nf * 16 + lr] : 0.f;

#pragma unroll
    for (int mf = 0; mf < 4; mf++) {
#pragma unroll
      for (int rg = 0; rg < 4; rg++) {
        int mt = wm * 64 + mf * 16 + kc * 4 + rg;
        int mrow = m0 + mt;
        if (mrow < cnt) {
          int tok = list[mrow];
          float w = (e < NEXP) ? weights[(size_t)tok * NEXP + e] : 1.0f;
          float* orow = out + (size_t)tok * DDIM + n0 + wn * 64 + lr;
#pragma unroll
          for (int nf = 0; nf < 4; nf++)
            atomicAdd(orow + nf * 16, w * (acc[mf][nf][rg] + biasv[nf]));
        }
      }
    }
    __builtin_amdgcn_s_barrier();
    __builtin_amdgcn_sched_barrier(0);
  }
}

// ---------------- launcher ----------------
extern "C" void kernel_launch(void* const* d_in, const int* in_sizes, int n_in,
                              void* d_out, int out_size, void* d_ws, size_t ws_size,
                              hipStream_t stream) {
  (void)in_sizes; (void)n_in; (void)out_size; (void)ws_size;
  const float* hidden   = (const float*)d_in[0];
  const float* router_w = (const float*)d_in[1];
  const float* router_b = (const float*)d_in[2];
  const float* sw1 = (const float*)d_in[3];
  const float* sb1 = (const float*)d_in[4];
  const float* sw2 = (const float*)d_in[5];
  const float* sb2 = (const float*)d_in[6];
  const float* rw1 = (const float*)d_in[7];
  const float* rb1 = (const float*)d_in[8];
  const float* rw2 = (const float*)d_in[9];
  const float* rb2 = (const float*)d_in[10];
  float* out = (float*)d_out;

  char* ws = (char*)d_ws;
  u16* Xb      = (u16*)(ws + 0);            //  4,194,304  [T][D] bf16
  u16* rw1t    = (u16*)(ws + 4194304);      // 33,554,432  [E][H][D] bf16 (B^T)
  u16* rw2t    = (u16*)(ws + 37748736);     // 33,554,432  [E][D][H] bf16 (B^T)
  u16* sw1t    = (u16*)(ws + 71303168);     //  4,194,304  [H][D]
  u16* sw2t    = (u16*)(ws + 75497472);     //  4,194,304  [D][H]
  u16* H1      = (u16*)(ws + 79691776);     // 25,165,824  [6144][H] bf16
  float* weights = (float*)(ws + 104857600);//     65,536  [T][E]
  int* counts  = (int*)(ws + 104923136);    //         64
  int* segoff  = (int*)(ws + 104923200);    //         64
  int* lists   = (int*)(ws + 104923264);    //     73,728  [NSEG][T]
  int* ytab    = (int*)(ws + 104996992);    //        640
  int* nyt     = (int*)(ws + 104997632);    //          4

  hipMemsetAsync(counts, 0, 64, stream);
  hipMemsetAsync(out, 0, (size_t)T_TOK * DDIM * sizeof(float), stream);

  router_kernel<<<T_TOK / 4, 256, 0, stream>>>(hidden, router_w, router_b, Xb,
                                               weights, counts, lists);
  seg_kernel<<<1, 1, 0, stream>>>(counts, segoff, ytab, nyt);

  transpose_bf16_kernel<<<dim3(HDIM / 32, DDIM / 32, NSEG), 256, 0, stream>>>(
      rw1, sw1, rw1t, sw1t, DDIM, HDIM);
  transpose_bf16_kernel<<<dim3(DDIM / 32, HDIM / 32, NSEG), 256, 0, stream>>>(
      rw2, sw2, rw2t, sw2t, HDIM, DDIM);

  gemm1_kernel<<<1024, 256, 0, stream>>>(
      Xb, rw1t, sw1t, rb1, sb1, counts, segoff, lists, ytab, nyt, H1);
  gemm2_kernel<<<1024, 256, 0, stream>>>(
      H1, rw2t, sw2t, rb2, sb2, weights, counts, segoff, lists, ytab, nyt, out);
}

// Round 7
// 248.923 us; speedup vs baseline: 1.1040x; 1.1040x over previous
//
#include <hip/hip_runtime.h>
#include <hip/hip_bf16.h>

#define T_TOK 2048
#define DDIM  1024
#define HDIM  2048
#define NEXP  8
#define NSEG  9   // 8 routed + 1 shared

typedef unsigned short u16;
typedef __attribute__((ext_vector_type(4))) float f32x4;
typedef __attribute__((ext_vector_type(8))) short bf16x8;
typedef __attribute__((ext_vector_type(4))) unsigned short u16x4;

__device__ __forceinline__ u16 f2bf(float x) {
  union { float f; unsigned int u; } v; v.f = x;
  unsigned int r = v.u + 0x7fffu + ((v.u >> 16) & 1u);
  return (u16)(r >> 16);
}
__device__ __forceinline__ float gelu_exact(float x) {
  return 0.5f * x * (1.0f + erff(x * 0.70710678118654752f));
}
// chunk swizzle for 64B rows (4 x 16B chunks)
__device__ __forceinline__ int swz4(int row) {
  return (row & 3) ^ ((row >> 2) & 3);
}

__device__ __forceinline__ void gload16(const void* g, void* l) {
  __builtin_amdgcn_global_load_lds(
      (const __attribute__((address_space(1))) unsigned int*)g,
      (__attribute__((address_space(3))) unsigned int*)l, 16, 0, 0);
}

// ---------------- router: logits, softmax, top-2, lists, bf16 X ----------------
__global__ __launch_bounds__(256) void router_kernel(
    const float* __restrict__ x, const float* __restrict__ rw,
    const float* __restrict__ rb, u16* __restrict__ xb,
    float* __restrict__ weights, int* __restrict__ counts,
    int* __restrict__ lists)
{
  int wv = threadIdx.x >> 6, lane = threadIdx.x & 63;
  int t = blockIdx.x * 4 + wv;            // one wave per token
  const float* xrow = x + (size_t)t * DDIM;
  float acc[NEXP];
#pragma unroll
  for (int e = 0; e < NEXP; e++) acc[e] = 0.f;
#pragma unroll
  for (int i = 0; i < 4; i++) {
    int d0 = i * 256 + lane * 4;
    f32x4 xv = *(const f32x4*)(xrow + d0);
    u16x4 pk;
#pragma unroll
    for (int j = 0; j < 4; j++) {
      float xs = xv[j];
      pk[j] = f2bf(xs);
      const float* wr = rw + (size_t)(d0 + j) * NEXP;
#pragma unroll
      for (int e = 0; e < NEXP; e++) acc[e] = fmaf(xs, wr[e], acc[e]);
    }
    *(u16x4*)(xb + (size_t)t * DDIM + d0) = pk;
  }
#pragma unroll
  for (int off = 32; off >= 1; off >>= 1)
#pragma unroll
    for (int e = 0; e < NEXP; e++) acc[e] += __shfl_xor(acc[e], off);

  if (lane == 0) {
    float lg[NEXP], mx = -1e30f;
#pragma unroll
    for (int e = 0; e < NEXP; e++) { lg[e] = acc[e] + rb[e]; mx = fmaxf(mx, lg[e]); }
    float p[NEXP], s = 0.f;
#pragma unroll
    for (int e = 0; e < NEXP; e++) { p[e] = expf(lg[e] - mx); s += p[e]; }
    float inv = 1.0f / s;
#pragma unroll
    for (int e = 0; e < NEXP; e++) p[e] *= inv;
    int i1 = 0;
#pragma unroll
    for (int e = 1; e < NEXP; e++) if (p[e] > p[i1]) i1 = e;
    int i2 = (i1 == 0) ? 1 : 0;
#pragma unroll
    for (int e = 0; e < NEXP; e++) if (e != i1 && p[e] > p[i2]) i2 = e;
#pragma unroll
    for (int e = 0; e < NEXP; e++)
      weights[(size_t)t * NEXP + e] = (e == i1) ? p[i1] : (e == i2) ? p[i2] : 0.f;
    int p1 = atomicAdd(counts + i1, 1); lists[i1 * T_TOK + p1] = t;
    int p2 = atomicAdd(counts + i2, 1); lists[i2 * T_TOK + p2] = t;
    lists[NEXP * T_TOK + t] = t;        // shared segment: identity
  }
}

// seg offsets + compact y-tile table (e*256+my for non-empty 256-row tiles)
__global__ void seg_kernel(int* counts, int* segoff, int* ytab, int* nyt) {
  counts[NEXP] = T_TOK;
  int off = 0, n = 0;
  for (int e = 0; e < NSEG; e++) {
    segoff[e] = off;
    int c = counts[e];
    for (int my = 0; my * 256 < c; my++) ytab[n++] = e * 256 + my;
    off += c;
  }
  *nyt = n;
}

// ------------- transpose + fp32->bf16 cast: [z][R][C] -> [z][C][R] -------------
__global__ __launch_bounds__(256) void transpose_bf16_kernel(
    const float* __restrict__ rin, const float* __restrict__ sin_,
    u16* __restrict__ rout, u16* __restrict__ sout, int R, int C)
{
  __shared__ float tile[32][33];
  int b = blockIdx.z;
  const float* inb = (b < NEXP) ? rin + (size_t)b * R * C : sin_;
  u16* outb = (b < NEXP) ? rout + (size_t)b * R * C : sout;
  int r0 = blockIdx.y * 32, c0 = blockIdx.x * 32;
  int tx = threadIdx.x & 31, ty = threadIdx.x >> 5;
#pragma unroll
  for (int j = 0; j < 4; j++) {
    int r = ty + j * 8;
    tile[r][tx] = inb[(size_t)(r0 + r) * C + c0 + tx];
  }
  __syncthreads();
#pragma unroll
  for (int j = 0; j < 4; j++) {
    int rr = ty + j * 8;
    outb[(size_t)(c0 + rr) * R + r0 + tx] = f2bf(tile[tx][rr]);
  }
}

// =====================================================================
// GEMM core v7: 256x256 tile, BK=32, 8 waves (2M x 4N; wave owns 128x64),
// FOUR LDS buffers (128 KB), DEPTH-2 prefetch, counted vmcnt, one raw
// barrier per K-step:
//   step s: issue stage(s+2 -> buf[(s+2)&3]); vmcnt(8); s_barrier;
//           ds_read frags(buf[s&3]); setprio(1); 32 MFMA; setprio(0)
// Race-freedom: writes at step s target buf (s+2)&3; concurrent waves are
// within one barrier of each other (steps s-1..s+1) reading bufs
// (s-1..s+1)&3 -- disjoint mod 4. ds_read(s) safety: each wave's
// vmcnt(8) (stages s+1,s+2 = 8 newer loads in flight) forces its own
// stage(s) landed BEFORE barrier(s); reads follow barrier(s).
// =====================================================================

// ---------------- GEMM1: H1 = gelu(gather(X) @ W1 + b1), bf16 out ----------------
__global__ __launch_bounds__(512) void gemm1_kernel(
    const u16* __restrict__ Xb, const u16* __restrict__ rw1t,
    const u16* __restrict__ sw1t, const float* __restrict__ rb1,
    const float* __restrict__ sb1, const int* __restrict__ counts,
    const int* __restrict__ segoff, const int* __restrict__ lists,
    const int* __restrict__ ytab, const int* __restrict__ nyt,
    u16* __restrict__ H1)
{
  __shared__ u16 Alds[4][256 * 32];   // 16 KB x4
  __shared__ u16 Blds[4][256 * 32];   // 16 KB x4

  int tid = threadIdx.x, lane = tid & 63;
  int wv = tid >> 6, wm = wv >> 2, wn = wv & 3;
  int kc = lane >> 4, lr = lane & 15;

  // staging: chunk i = j*512+tid (j=0,1); row=i>>2, dest chunk=i&3 (linear
  // dest); global source chunk = (i&3) ^ swz4(row)
  int srow[2], soff[2];
#pragma unroll
  for (int j = 0; j < 2; j++) {
    int i = j * 512 + tid;
    srow[j] = i >> 2;
    soff[j] = (((i & 3) ^ swz4(i >> 2)) * 8);
  }
  // fragment read offsets (elems): row r, chunk kc ^ swz4(r)
  int aoff[8], boff[4];
#pragma unroll
  for (int f = 0; f < 8; f++) {
    int ra = wm * 128 + f * 16 + lr;
    aoff[f] = ra * 32 + ((kc ^ swz4(ra)) * 8);
  }
#pragma unroll
  for (int f = 0; f < 4; f++) {
    int rb_ = wn * 64 + f * 16 + lr;
    boff[f] = rb_ * 32 + ((kc ^ swz4(rb_)) * 8);
  }

  int ntile = nyt[0] * (HDIM / 256);   // ~24 x 8 = ~192 tiles
  for (int t = blockIdx.x; t < ntile; t += gridDim.x) {
    int yt = t >> 3, nx = t & 7;
    int em = ytab[yt];
    int e = em >> 8, m0 = (em & 255) * 256, n0 = nx * 256;
    int cnt = counts[e];
    const u16* Bt = (e < NEXP) ? (rw1t + (size_t)e * HDIM * DDIM) : sw1t;
    const float* bias = (e < NEXP) ? (rb1 + (size_t)e * HDIM) : sb1;
    const int* list = lists + e * T_TOK;
    int seg = segoff[e];

    size_t abase[2], bbase[2];
#pragma unroll
    for (int j = 0; j < 2; j++) {
      int tok = list[min(m0 + srow[j], cnt - 1)];
      abase[j] = (size_t)tok * DDIM + soff[j];
      bbase[j] = (size_t)(n0 + srow[j]) * DDIM + soff[j];
    }

    f32x4 acc[8][4];
#pragma unroll
    for (int i = 0; i < 8; i++)
#pragma unroll
      for (int j = 0; j < 4; j++) acc[i][j] = (f32x4){0.f, 0.f, 0.f, 0.f};

    const int NS = DDIM / 32;   // 32 steps
    // prologue: stage steps 0 and 1 into bufs 0,1 (8 loads in flight)
#pragma unroll
    for (int s = 0; s < 2; s++)
#pragma unroll
      for (int j = 0; j < 2; j++) {
        int i = j * 512 + tid;
        gload16(Xb + abase[j] + s * 32, &Alds[s][i * 8]);
        gload16(Bt + bbase[j] + s * 32, &Blds[s][i * 8]);
      }

    for (int s = 0; s < NS; s++) {
      if (s + 2 < NS) {
        int kk = (s + 2) * 32;
        int nb = (s + 2) & 3;
#pragma unroll
        for (int j = 0; j < 2; j++) {
          int i = j * 512 + tid;
          gload16(Xb + abase[j] + kk, &Alds[nb][i * 8]);
          gload16(Bt + bbase[j] + kk, &Blds[nb][i * 8]);
        }
        asm volatile("s_waitcnt vmcnt(8)" ::: "memory");
      } else if (s + 1 < NS) {
        asm volatile("s_waitcnt vmcnt(4)" ::: "memory");
      } else {
        asm volatile("s_waitcnt vmcnt(0)" ::: "memory");
      }
      __builtin_amdgcn_s_barrier();
      __builtin_amdgcn_sched_barrier(0);

      const u16* Ac = &Alds[s & 3][0];
      const u16* Bc = &Blds[s & 3][0];
      bf16x8 af[8], bfr[4];
#pragma unroll
      for (int f = 0; f < 8; f++) af[f] = *(const bf16x8*)(Ac + aoff[f]);
#pragma unroll
      for (int f = 0; f < 4; f++) bfr[f] = *(const bf16x8*)(Bc + boff[f]);
      __builtin_amdgcn_s_setprio(1);
#pragma unroll
      for (int mf = 0; mf < 8; mf++)
#pragma unroll
        for (int nf = 0; nf < 4; nf++)
          acc[mf][nf] = __builtin_amdgcn_mfma_f32_16x16x32_bf16(af[mf], bfr[nf], acc[mf][nf], 0, 0, 0);
      __builtin_amdgcn_s_setprio(0);
    }

#pragma unroll
    for (int nf = 0; nf < 4; nf++) {
      int col = n0 + wn * 64 + nf * 16 + lr;
      float b = bias[col];
#pragma unroll
      for (int mf = 0; mf < 8; mf++) {
#pragma unroll
        for (int rg = 0; rg < 4; rg++) {
          int mt = wm * 128 + mf * 16 + kc * 4 + rg;
          if (m0 + mt < cnt) {
            float v = acc[mf][nf][rg] + b;
            H1[(size_t)(seg + m0 + mt) * HDIM + col] = f2bf(gelu_exact(v));
          }
        }
      }
    }
    // protect LDS (steps NS-2/NS-1 read bufs 2,3; next tile stages 0,1 --
    // disjoint, but keep a barrier so reads complete before reuse wraps)
    __builtin_amdgcn_s_barrier();
    __builtin_amdgcn_sched_barrier(0);
  }
}

// ------------- GEMM2: out[tok] += w * (H1seg @ W2 + b2), fp32 atomics -------------
// K split in 2 halves of 1024 (bias added by half 0 only).
__global__ __launch_bounds__(512) void gemm2_kernel(
    const u16* __restrict__ H1, const u16* __restrict__ rw2t,
    const u16* __restrict__ sw2t, const float* __restrict__ rb2,
    const float* __restrict__ sb2, const float* __restrict__ weights,
    const int* __restrict__ counts, const int* __restrict__ segoff,
    const int* __restrict__ lists, const int* __restrict__ ytab,
    const int* __restrict__ nyt, float* __restrict__ out)
{
  __shared__ u16 Alds[4][256 * 32];
  __shared__ u16 Blds[4][256 * 32];

  int tid = threadIdx.x, lane = tid & 63;
  int wv = tid >> 6, wm = wv >> 2, wn = wv & 3;
  int kc = lane >> 4, lr = lane & 15;

  int srow[2], soff[2];
#pragma unroll
  for (int j = 0; j < 2; j++) {
    int i = j * 512 + tid;
    srow[j] = i >> 2;
    soff[j] = (((i & 3) ^ swz4(i >> 2)) * 8);
  }
  int aoff[8], boff[4];
#pragma unroll
  for (int f = 0; f < 8; f++) {
    int ra = wm * 128 + f * 16 + lr;
    aoff[f] = ra * 32 + ((kc ^ swz4(ra)) * 8);
  }
#pragma unroll
  for (int f = 0; f < 4; f++) {
    int rb_ = wn * 64 + f * 16 + lr;
    boff[f] = rb_ * 32 + ((kc ^ swz4(rb_)) * 8);
  }

  int ntile = nyt[0] * (DDIM / 256) * 2;   // ~24 x 4 x 2 = ~192
  for (int t = blockIdx.x; t < ntile; t += gridDim.x) {
    int kh = t & 1, nx = (t >> 1) & 3, yt = t >> 3;
    int em = ytab[yt];
    int e = em >> 8, m0 = (em & 255) * 256, n0 = nx * 256;
    int cnt = counts[e];
    const u16* Bt = (e < NEXP) ? (rw2t + (size_t)e * DDIM * HDIM) : sw2t;
    const float* bias = (e < NEXP) ? (rb2 + (size_t)e * DDIM) : sb2;
    const int* list = lists + e * T_TOK;
    int seg = segoff[e];
    int k0 = kh * 1024;

    size_t abase[2], bbase[2];
#pragma unroll
    for (int j = 0; j < 2; j++) {
      abase[j] = (size_t)(seg + min(m0 + srow[j], cnt - 1)) * HDIM + k0 + soff[j];
      bbase[j] = (size_t)(n0 + srow[j]) * HDIM + k0 + soff[j];
    }

    f32x4 acc[8][4];
#pragma unroll
    for (int i = 0; i < 8; i++)
#pragma unroll
      for (int j = 0; j < 4; j++) acc[i][j] = (f32x4){0.f, 0.f, 0.f, 0.f};

    const int NS = 1024 / 32;   // 32 steps
#pragma unroll
    for (int s = 0; s < 2; s++)
#pragma unroll
      for (int j = 0; j < 2; j++) {
        int i = j * 512 + tid;
        gload16(H1 + abase[j] + s * 32, &Alds[s][i * 8]);
        gload16(Bt + bbase[j] + s * 32, &Blds[s][i * 8]);
      }

    for (int s = 0; s < NS; s++) {
      if (s + 2 < NS) {
        int kk = (s + 2) * 32;
        int nb = (s + 2) & 3;
#pragma unroll
        for (int j = 0; j < 2; j++) {
          int i = j * 512 + tid;
          gload16(H1 + abase[j] + kk, &Alds[nb][i * 8]);
          gload16(Bt + bbase[j] + kk, &Blds[nb][i * 8]);
        }
        asm volatile("s_waitcnt vmcnt(8)" ::: "memory");
      } else if (s + 1 < NS) {
        asm volatile("s_waitcnt vmcnt(4)" ::: "memory");
      } else {
        asm volatile("s_waitcnt vmcnt(0)" ::: "memory");
      }
      __builtin_amdgcn_s_barrier();
      __builtin_amdgcn_sched_barrier(0);

      const u16* Ac = &Alds[s & 3][0];
      const u16* Bc = &Blds[s & 3][0];
      bf16x8 af[8], bfr[4];
#pragma unroll
      for (int f = 0; f < 8; f++) af[f] = *(const bf16x8*)(Ac + aoff[f]);
#pragma unroll
      for (int f = 0; f < 4; f++) bfr[f] = *(const bf16x8*)(Bc + boff[f]);
      __builtin_amdgcn_s_setprio(1);
#pragma unroll
      for (int mf = 0; mf < 8; mf++)
#pragma unroll
        for (int nf = 0; nf < 4; nf++)
          acc[mf][nf] = __builtin_amdgcn_mfma_f32_16x16x32_bf16(af[mf], bfr[nf], acc[mf][nf], 0, 0, 0);
      __builtin_amdgcn_s_setprio(0);
    }

    float biasv[4];
#pragma unroll
    for (int nf = 0; nf < 4; nf++)
      biasv[nf] = (kh == 0) ? bias[n0 + wn * 64 + nf * 16 + lr] : 0.f;

#pragma unroll
    for (int mf = 0; mf < 8; mf++) {
#pragma unroll
      for (int rg = 0; rg < 4; rg++) {
        int mt = wm * 128 + mf * 16 + kc * 4 + rg;
        int mrow = m0 + mt;
        if (mrow < cnt) {
          int tok = list[mrow];
          float w = (e < NEXP) ? weights[(size_t)tok * NEXP + e] : 1.0f;
          float* orow = out + (size_t)tok * DDIM + n0 + wn * 64 + lr;
#pragma unroll
          for (int nf = 0; nf < 4; nf++)
            atomicAdd(orow + nf * 16, w * (acc[mf][nf][rg] + biasv[nf]));
        }
      }
    }
    __builtin_amdgcn_s_barrier();
    __builtin_amdgcn_sched_barrier(0);
  }
}

// ---------------- launcher ----------------
extern "C" void kernel_launch(void* const* d_in, const int* in_sizes, int n_in,
                              void* d_out, int out_size, void* d_ws, size_t ws_size,
                              hipStream_t stream) {
  (void)in_sizes; (void)n_in; (void)out_size; (void)ws_size;
  const float* hidden   = (const float*)d_in[0];
  const float* router_w = (const float*)d_in[1];
  const float* router_b = (const float*)d_in[2];
  const float* sw1 = (const float*)d_in[3];
  const float* sb1 = (const float*)d_in[4];
  const float* sw2 = (const float*)d_in[5];
  const float* sb2 = (const float*)d_in[6];
  const float* rw1 = (const float*)d_in[7];
  const float* rb1 = (const float*)d_in[8];
  const float* rw2 = (const float*)d_in[9];
  const float* rb2 = (const float*)d_in[10];
  float* out = (float*)d_out;

  char* ws = (char*)d_ws;
  u16* Xb      = (u16*)(ws + 0);            //  4,194,304  [T][D] bf16
  u16* rw1t    = (u16*)(ws + 4194304);      // 33,554,432  [E][H][D] bf16 (B^T)
  u16* rw2t    = (u16*)(ws + 37748736);     // 33,554,432  [E][D][H] bf16 (B^T)
  u16* sw1t    = (u16*)(ws + 71303168);     //  4,194,304  [H][D]
  u16* sw2t    = (u16*)(ws + 75497472);     //  4,194,304  [D][H]
  u16* H1      = (u16*)(ws + 79691776);     // 25,165,824  [6144][H] bf16
  float* weights = (float*)(ws + 104857600);//     65,536  [T][E]
  int* counts  = (int*)(ws + 104923136);    //         64
  int* segoff  = (int*)(ws + 104923200);    //         64
  int* lists   = (int*)(ws + 104923264);    //     73,728  [NSEG][T]
  int* ytab    = (int*)(ws + 104996992);    //        640
  int* nyt     = (int*)(ws + 104997632);    //          4

  hipMemsetAsync(counts, 0, 64, stream);
  hipMemsetAsync(out, 0, (size_t)T_TOK * DDIM * sizeof(float), stream);

  router_kernel<<<T_TOK / 4, 256, 0, stream>>>(hidden, router_w, router_b, Xb,
                                               weights, counts, lists);
  seg_kernel<<<1, 1, 0, stream>>>(counts, segoff, ytab, nyt);

  transpose_bf16_kernel<<<dim3(HDIM / 32, DDIM / 32, NSEG), 256, 0, stream>>>(
      rw1, sw1, rw1t, sw1t, DDIM, HDIM);
  transpose_bf16_kernel<<<dim3(DDIM / 32, HDIM / 32, NSEG), 256, 0, stream>>>(
      rw2, sw2, rw2t, sw2t, HDIM, DDIM);

  gemm1_kernel<<<256, 512, 0, stream>>>(
      Xb, rw1t, sw1t, rb1, sb1, counts, segoff, lists, ytab, nyt, H1);
  gemm2_kernel<<<256, 512, 0, stream>>>(
      H1, rw2t, sw2t, rb2, sb2, weights, counts, segoff, lists, ytab, nyt, out);
}